// Round 6
// baseline (95.169 us; speedup 1.0000x reference)
//
#include <hip/hip_runtime.h>

// Problem constants (fixed by the reference)
#define BB 2048
#define CC 50
#define DD 512
#define HH 51   // D // 10

static __device__ __forceinline__ float dot4(const float4 a, const float4 b) {
    return a.x * b.x + a.y * b.y + a.z * b.z + a.w * b.w;
}

// ---------------- Kernel 1: head scores -> ws ----------------
// grid (7, BB), block 256. wave handles scores c0 = 8*bx + 2*wave, c0+1.
__global__ __launch_bounds__(256) void score_kernel(
    const float* __restrict__ q,      // [B, D]
    const int*   __restrict__ heads,  // [B, C]
    const float* __restrict__ ent,    // [NE+1, D]
    float* __restrict__ ws_sc)        // [B, C]
{
    const int b    = blockIdx.y;
    const int wave = threadIdx.x >> 6;
    const int lane = threadIdx.x & 63;
    const int c0   = blockIdx.x * 8 + wave * 2;
    if (c0 >= CC) return;
    const bool v1 = (c0 + 1 < CC);

    const int hi0 = heads[b * CC + c0];
    const int hi1 = v1 ? heads[b * CC + c0 + 1] : 0;

    const float4* qrow = (const float4*)(q + (size_t)b * DD);
    const float4* hr0  = (const float4*)(ent + (size_t)hi0 * DD);
    const float4* hr1  = (const float4*)(ent + (size_t)hi1 * DD);

    // 6 independent load-pairs in flight, then one implicit wait at first use
    const float4 q0 = qrow[lane];
    const float4 q1 = qrow[lane + 64];
    const float4 a0 = hr0[lane];
    const float4 a1 = hr0[lane + 64];
    const float4 b0 = hr1[lane];
    const float4 b1 = hr1[lane + 64];

    float p0 = dot4(q0, a0) + dot4(q1, a1);
    float p1 = dot4(q0, b0) + dot4(q1, b1);
    #pragma unroll
    for (int off = 32; off > 0; off >>= 1) {
        p0 += __shfl_xor(p0, off, 64);
        p1 += __shfl_xor(p1, off, 64);
    }
    if (lane == 0) {
        ws_sc[b * CC + c0] = p0;
        if (v1) ws_sc[b * CC + c0 + 1] = p1;
    }
}

// ---------------- Kernel 2: pooling + FFN + residual ----------------
// grid BB, block 256 (4 waves). wave w handles c = w + 4i, i = 0..12 (padded to 52).
__global__ __launch_bounds__(256) void fuse_kernel(
    const float* __restrict__ q,      // [B, D]
    const int*   __restrict__ tails,  // [B, C]
    const int*   __restrict__ rels,   // [B, C]
    const float* __restrict__ ent,    // [NE+1, D]
    const float* __restrict__ rel,    // [NR+1, D]
    const float* __restrict__ w1,     // [D, H]
    const float* __restrict__ b1,     // [H]
    const float* __restrict__ w2,     // [H, D]
    const float* __restrict__ b2,     // [D]
    const float* __restrict__ ws_sc,  // [B, C]
    float* __restrict__ out)          // [B, D]
{
    const int b    = blockIdx.x;
    const int tid  = threadIdx.x;
    const int wave = tid >> 6;
    const int lane = tid & 63;

    __shared__ float  s_q[DD];          // 2 KB
    __shared__ float4 s_pp[4][128];     // 8 KB — per-wave pooled partials; reused for epilogue reduce
    __shared__ float  s_pool[DD];       // 2 KB
    __shared__ float  s_wred[4][HH];
    __shared__ float  s_mid[HH];
    __shared__ float  s_sc[52];
    __shared__ int    s_t[52], s_r[52];

    if (tid < 52) {
        const bool v = tid < CC;
        s_sc[tid] = v ? ws_sc[b * CC + tid] : 0.f;
        s_t[tid]  = v ? tails[b * CC + tid] : 0;
        s_r[tid]  = v ? rels [b * CC + tid] : 0;
    }
    if (tid < 128) {
        ((float4*)s_q)[tid] = ((const float4*)(q + (size_t)b * DD))[tid];
    }
    __syncthreads();

    // ---- pooling: pure load+FMA stream, rotating depth-2 prefetch ----
    float4 acc0 = make_float4(0.f, 0.f, 0.f, 0.f);
    float4 acc1 = make_float4(0.f, 0.f, 0.f, 0.f);
    {
        const float4* tp = (const float4*)(ent + (size_t)s_t[wave] * DD);
        const float4* rp = (const float4*)(rel + (size_t)s_r[wave] * DD);
        float4 t0 = tp[lane], t1 = tp[lane + 64];
        float4 r0 = rp[lane], r1 = rp[lane + 64];
        #pragma unroll
        for (int i = 0; i < 13; ++i) {
            float4 nt0, nt1, nr0, nr1;
            if (i < 12) {
                const int cn = wave + 4 * (i + 1);
                const float4* tn = (const float4*)(ent + (size_t)s_t[cn] * DD);
                const float4* rn = (const float4*)(rel + (size_t)s_r[cn] * DD);
                nt0 = tn[lane]; nt1 = tn[lane + 64];
                nr0 = rn[lane]; nr1 = rn[lane + 64];
            }
            const float p = s_sc[wave + 4 * i];
            acc0.x += p * (t0.x + r0.x);
            acc0.y += p * (t0.y + r0.y);
            acc0.z += p * (t0.z + r0.z);
            acc0.w += p * (t0.w + r0.w);
            acc1.x += p * (t1.x + r1.x);
            acc1.y += p * (t1.y + r1.y);
            acc1.z += p * (t1.z + r1.z);
            acc1.w += p * (t1.w + r1.w);
            t0 = nt0; t1 = nt1; r0 = nr0; r1 = nr1;
        }
    }
    s_pp[wave][lane]      = acc0;
    s_pp[wave][lane + 64] = acc1;
    __syncthreads();

    // ---- reduce 4 per-wave partials -> s_pool ----
    if (tid < 128) {
        const float4 a0 = s_pp[0][tid];
        const float4 a1 = s_pp[1][tid];
        const float4 a2 = s_pp[2][tid];
        const float4 a3 = s_pp[3][tid];
        float4 s;
        s.x = a0.x + a1.x + a2.x + a3.x;
        s.y = a0.y + a1.y + a2.y + a3.y;
        s.z = a0.z + a1.z + a2.z + a3.z;
        s.w = a0.w + a1.w + a2.w + a3.w;
        ((float4*)s_pool)[tid] = s;
    }
    __syncthreads();

    // ---- phase 3: mid = relu(pooled @ w1 + b1); wave w owns d in [128w, 128w+128) ----
    if (lane < HH) {
        const int d0 = wave * 128;
        float partial = 0.f;
        #pragma unroll 8
        for (int j = 0; j < 128; ++j) {
            partial += s_pool[d0 + j] * w1[(size_t)(d0 + j) * HH + lane];
        }
        s_wred[wave][lane] = partial;
    }
    __syncthreads();
    if (tid < HH) {
        float m = b1[tid] + s_wred[0][tid] + s_wred[1][tid] + s_wred[2][tid] + s_wred[3][tid];
        s_mid[tid] = m > 0.f ? m : 0.f;
    }
    __syncthreads();

    // ---- phase 4: out = mid @ w2 + b2 + q ----
    const int cg = tid >> 7;    // 0..1
    const int dv = tid & 127;   // float4 index within row
    float4 acc2 = make_float4(0.f, 0.f, 0.f, 0.f);
    #pragma unroll
    for (int i = 0; i < 26; ++i) {
        const int h = cg + 2 * i;
        if (h < HH) {
            const float  m  = s_mid[h];
            const float4 wv = ((const float4*)(w2 + (size_t)h * DD))[dv];
            acc2.x += m * wv.x;
            acc2.y += m * wv.y;
            acc2.z += m * wv.z;
            acc2.w += m * wv.w;
        }
    }
    float4 (*s_red4)[128] = (float4 (*)[128])s_pp;   // reuse dead LDS
    s_red4[cg][dv] = acc2;
    __syncthreads();
    if (tid < 128) {
        const float4 a0 = s_red4[0][tid];
        const float4 a1 = s_red4[1][tid];
        const float4 bb = ((const float4*)b2)[tid];
        const float4 qq = ((const float4*)s_q)[tid];
        float4 o;
        o.x = a0.x + a1.x + bb.x + qq.x;
        o.y = a0.y + a1.y + bb.y + qq.y;
        o.z = a0.z + a1.z + bb.z + qq.z;
        o.w = a0.w + a1.w + bb.w + qq.w;
        ((float4*)(out + (size_t)b * DD))[tid] = o;
    }
}

extern "C" void kernel_launch(void* const* d_in, const int* in_sizes, int n_in,
                              void* d_out, int out_size, void* d_ws, size_t ws_size,
                              hipStream_t stream) {
    const float* q     = (const float*)d_in[0];
    const int*   heads = (const int*)  d_in[1];
    const int*   tails = (const int*)  d_in[2];
    const int*   rels  = (const int*)  d_in[3];
    const float* ent   = (const float*)d_in[4];
    const float* rel   = (const float*)d_in[5];
    const float* w1    = (const float*)d_in[6];
    const float* b1    = (const float*)d_in[7];
    const float* w2    = (const float*)d_in[8];
    const float* b2    = (const float*)d_in[9];
    float* out   = (float*)d_out;
    float* ws_sc = (float*)d_ws;      // [B, C] scores, 400 KB

    dim3 g1(7, BB, 1);
    score_kernel<<<g1, 256, 0, stream>>>(q, heads, ent, ws_sc);
    fuse_kernel<<<BB, 256, 0, stream>>>(q, tails, rels, ent, rel,
                                        w1, b1, w2, b2, ws_sc, out);
}

// Round 7
// 92.545 us; speedup vs baseline: 1.0283x; 1.0283x over previous
//
#include <hip/hip_runtime.h>

// Problem constants (fixed by the reference)
#define BB 2048
#define CC 50
#define DD 512
#define HH 51     // D // 10
#define NSPLIT 4  // gather blocks per batch row
#define CPB 13    // constraints per gather block (4*13 = 52 >= 50)

static __device__ __forceinline__ float dot4(const float4 a, const float4 b) {
    return a.x * b.x + a.y * b.y + a.z * b.z + a.w * b.w;
}

// ---------------- Kernel 1: gather (scores + partial pooling) ----------------
// grid (NSPLIT, BB), block 512 (8 waves). Block cb handles c = cb*13 .. cb*13+12.
// Wave w does k = w (all waves) and k = w+8 (waves 0-4): 2 serial iterations.
// Body is R3's proven merged score+pool stream.
__global__ __launch_bounds__(512) void gather_kernel(
    const float* __restrict__ q,      // [B, D]
    const int*   __restrict__ heads,  // [B, C]
    const int*   __restrict__ tails,  // [B, C]
    const int*   __restrict__ rels,   // [B, C]
    const float* __restrict__ ent,    // [NE+1, D]
    const float* __restrict__ rel,    // [NR+1, D]
    float* __restrict__ ws_pp)        // [B, NSPLIT, D] partial pooled
{
    const int cb   = blockIdx.x;
    const int b    = blockIdx.y;
    const int tid  = threadIdx.x;
    const int wave = tid >> 6;
    const int lane = tid & 63;

    __shared__ float  s_q[DD];          // 2 KB
    __shared__ float4 s_pp[8][128];     // 16 KB per-wave partials
    __shared__ int    s_h[16], s_t[16], s_r[16];

    if (tid < 16) {
        const int  c = cb * CPB + tid;
        const bool v = (tid < CPB) && (c < CC);
        s_h[tid] = v ? heads[b * CC + c] : 0;
        s_t[tid] = v ? tails[b * CC + c] : 0;
        s_r[tid] = v ? rels [b * CC + c] : 0;
    }
    if (tid < 128) {
        ((float4*)s_q)[tid] = ((const float4*)(q + (size_t)b * DD))[tid];
    }
    __syncthreads();

    const float4 q0 = ((const float4*)s_q)[lane];
    const float4 q1 = ((const float4*)s_q)[lane + 64];

    float4 acc0 = make_float4(0.f, 0.f, 0.f, 0.f);
    float4 acc1 = make_float4(0.f, 0.f, 0.f, 0.f);

    #pragma unroll
    for (int it = 0; it < 2; ++it) {
        const int k = wave + it * 8;
        if (k < CPB) {                              // wave-uniform branch
            const int c = cb * CPB + k;
            const float4* hrow = (const float4*)(ent + (size_t)s_h[k] * DD);
            const float4* trow = (const float4*)(ent + (size_t)s_t[k] * DD);
            const float4* rrow = (const float4*)(rel + (size_t)s_r[k] * DD);
            const float4 h0 = hrow[lane];
            const float4 h1 = hrow[lane + 64];
            const float4 t0 = trow[lane];
            const float4 t1 = trow[lane + 64];
            const float4 r0 = rrow[lane];
            const float4 r1 = rrow[lane + 64];
            float p = dot4(q0, h0) + dot4(q1, h1);
            #pragma unroll
            for (int off = 32; off > 0; off >>= 1) p += __shfl_xor(p, off, 64);
            p = (c < CC) ? p : 0.f;                 // mask pad constraints
            acc0.x += p * (t0.x + r0.x);
            acc0.y += p * (t0.y + r0.y);
            acc0.z += p * (t0.z + r0.z);
            acc0.w += p * (t0.w + r0.w);
            acc1.x += p * (t1.x + r1.x);
            acc1.y += p * (t1.y + r1.y);
            acc1.z += p * (t1.z + r1.z);
            acc1.w += p * (t1.w + r1.w);
        }
    }
    s_pp[wave][lane]      = acc0;
    s_pp[wave][lane + 64] = acc1;
    __syncthreads();

    // reduce 8 per-wave partials -> ws
    if (tid < 128) {
        float4 s = s_pp[0][tid];
        #pragma unroll
        for (int w = 1; w < 8; ++w) {
            const float4 a = s_pp[w][tid];
            s.x += a.x; s.y += a.y; s.z += a.z; s.w += a.w;
        }
        ((float4*)(ws_pp + ((size_t)b * NSPLIT + cb) * DD))[tid] = s;
    }
}

// ---------------- Kernel 2: reduce partials + FFN + residual ----------------
// grid BB, block 512 (8 waves) — R1's proven epilogue.
__global__ __launch_bounds__(512) void ffn_kernel(
    const float* __restrict__ q,      // [B, D]
    const float* __restrict__ ws_pp,  // [B, NSPLIT, D]
    const float* __restrict__ w1,     // [D, H]
    const float* __restrict__ b1,     // [H]
    const float* __restrict__ w2,     // [H, D]
    const float* __restrict__ b2,     // [D]
    float* __restrict__ out)          // [B, D]
{
    const int b    = blockIdx.x;
    const int tid  = threadIdx.x;
    const int wave = tid >> 6;
    const int lane = tid & 63;

    __shared__ float  s_q[DD];
    __shared__ float  s_pool[DD];
    __shared__ float  s_wred[8][HH];
    __shared__ float  s_mid[HH];
    __shared__ float4 s_red4[4][128];

    if (tid < 128) {
        ((float4*)s_q)[tid] = ((const float4*)(q + (size_t)b * DD))[tid];
        const float4* pp = (const float4*)(ws_pp + (size_t)b * NSPLIT * DD);
        const float4 a0 = pp[tid];
        const float4 a1 = pp[128 + tid];
        const float4 a2 = pp[256 + tid];
        const float4 a3 = pp[384 + tid];
        float4 s;
        s.x = a0.x + a1.x + a2.x + a3.x;
        s.y = a0.y + a1.y + a2.y + a3.y;
        s.z = a0.z + a1.z + a2.z + a3.z;
        s.w = a0.w + a1.w + a2.w + a3.w;
        ((float4*)s_pool)[tid] = s;
    }
    __syncthreads();

    // mid = relu(pooled @ w1 + b1); wave w owns d in [64w, 64w+64)
    if (lane < HH) {
        const int d0 = wave * 64;
        float partial = 0.f;
        #pragma unroll 8
        for (int j = 0; j < 64; ++j) {
            partial += s_pool[d0 + j] * w1[(size_t)(d0 + j) * HH + lane];
        }
        s_wred[wave][lane] = partial;
    }
    __syncthreads();
    if (tid < HH) {
        float m = b1[tid];
        #pragma unroll
        for (int w = 0; w < 8; ++w) m += s_wred[w][tid];
        s_mid[tid] = m > 0.f ? m : 0.f;
    }
    __syncthreads();

    // out = mid @ w2 + b2 + q
    const int cg = tid >> 7;    // 0..3
    const int dv = tid & 127;
    float4 acc2 = make_float4(0.f, 0.f, 0.f, 0.f);
    #pragma unroll
    for (int i = 0; i < 13; ++i) {
        const int h = cg + i * 4;
        if (h < HH) {
            const float  m  = s_mid[h];
            const float4 wv = ((const float4*)(w2 + (size_t)h * DD))[dv];
            acc2.x += m * wv.x;
            acc2.y += m * wv.y;
            acc2.z += m * wv.z;
            acc2.w += m * wv.w;
        }
    }
    s_red4[cg][dv] = acc2;
    __syncthreads();
    if (tid < 128) {
        const float4 a0 = s_red4[0][tid];
        const float4 a1 = s_red4[1][tid];
        const float4 a2 = s_red4[2][tid];
        const float4 a3 = s_red4[3][tid];
        const float4 bb = ((const float4*)b2)[tid];
        const float4 qq = ((const float4*)s_q)[tid];
        float4 o;
        o.x = a0.x + a1.x + a2.x + a3.x + bb.x + qq.x;
        o.y = a0.y + a1.y + a2.y + a3.y + bb.y + qq.y;
        o.z = a0.z + a1.z + a2.z + a3.z + bb.z + qq.z;
        o.w = a0.w + a1.w + a2.w + a3.w + bb.w + qq.w;
        ((float4*)(out + (size_t)b * DD))[tid] = o;
    }
}

// ---------------- Fallback: R3 monolithic kernel (known-good 72.9 us) --------
__global__ __launch_bounds__(512) void mono_kernel(
    const float* __restrict__ q,
    const int*   __restrict__ heads,
    const int*   __restrict__ tails,
    const int*   __restrict__ rels,
    const float* __restrict__ ent,
    const float* __restrict__ rel,
    const float* __restrict__ w1,
    const float* __restrict__ b1,
    const float* __restrict__ w2,
    const float* __restrict__ b2,
    float* __restrict__ out)
{
    const int b    = blockIdx.x;
    const int tid  = threadIdx.x;
    const int wave = tid >> 6;
    const int lane = tid & 63;

    __shared__ float  s_q[DD];
    __shared__ float4 s_pp[8][128];
    __shared__ float  s_pool[DD];
    __shared__ float  s_wred[8][HH];
    __shared__ float  s_mid[HH];
    __shared__ int    s_h[CC], s_t[CC], s_r[CC];

    if (tid < CC) {
        s_h[tid] = heads[b * CC + tid];
        s_t[tid] = tails[b * CC + tid];
        s_r[tid] = rels [b * CC + tid];
    }
    if (tid < 128) {
        ((float4*)s_q)[tid] = ((const float4*)(q + (size_t)b * DD))[tid];
    }
    __syncthreads();

    const float4 q0 = ((const float4*)s_q)[lane * 2];
    const float4 q1 = ((const float4*)s_q)[lane * 2 + 1];

    float4 acc0 = make_float4(0.f, 0.f, 0.f, 0.f);
    float4 acc1 = make_float4(0.f, 0.f, 0.f, 0.f);
    #pragma unroll 2
    for (int c = wave; c < CC; c += 8) {
        const float4* hrow = (const float4*)(ent + (size_t)s_h[c] * DD);
        const float4* trow = (const float4*)(ent + (size_t)s_t[c] * DD);
        const float4* rrow = (const float4*)(rel + (size_t)s_r[c] * DD);
        const float4 h0 = hrow[lane * 2];
        const float4 h1 = hrow[lane * 2 + 1];
        const float4 t0 = trow[lane * 2];
        const float4 t1 = trow[lane * 2 + 1];
        const float4 r0 = rrow[lane * 2];
        const float4 r1 = rrow[lane * 2 + 1];
        float p = dot4(q0, h0) + dot4(q1, h1);
        #pragma unroll
        for (int off = 32; off > 0; off >>= 1) p += __shfl_xor(p, off, 64);
        acc0.x += p * (t0.x + r0.x);
        acc0.y += p * (t0.y + r0.y);
        acc0.z += p * (t0.z + r0.z);
        acc0.w += p * (t0.w + r0.w);
        acc1.x += p * (t1.x + r1.x);
        acc1.y += p * (t1.y + r1.y);
        acc1.z += p * (t1.z + r1.z);
        acc1.w += p * (t1.w + r1.w);
    }
    s_pp[wave][lane * 2]     = acc0;
    s_pp[wave][lane * 2 + 1] = acc1;
    __syncthreads();

    if (tid < 128) {
        float4 s = s_pp[0][tid];
        #pragma unroll
        for (int w = 1; w < 8; ++w) {
            const float4 a = s_pp[w][tid];
            s.x += a.x; s.y += a.y; s.z += a.z; s.w += a.w;
        }
        ((float4*)s_pool)[tid] = s;
    }
    __syncthreads();

    if (lane < HH) {
        const int d0 = wave * 64;
        float partial = 0.f;
        #pragma unroll 8
        for (int j = 0; j < 64; ++j) {
            partial += s_pool[d0 + j] * w1[(size_t)(d0 + j) * HH + lane];
        }
        s_wred[wave][lane] = partial;
    }
    __syncthreads();
    if (tid < HH) {
        float m = b1[tid];
        #pragma unroll
        for (int w = 0; w < 8; ++w) m += s_wred[w][tid];
        s_mid[tid] = m > 0.f ? m : 0.f;
    }
    __syncthreads();

    const int cg = tid >> 7;
    const int dv = tid & 127;
    float4 acc2 = make_float4(0.f, 0.f, 0.f, 0.f);
    #pragma unroll
    for (int i = 0; i < 13; ++i) {
        const int h = cg + i * 4;
        if (h < HH) {
            const float  m  = s_mid[h];
            const float4 wv = ((const float4*)(w2 + (size_t)h * DD))[dv];
            acc2.x += m * wv.x;
            acc2.y += m * wv.y;
            acc2.z += m * wv.z;
            acc2.w += m * wv.w;
        }
    }
    float4 (*s_red4)[128] = (float4 (*)[128])s_pp;
    s_red4[cg][dv] = acc2;
    __syncthreads();
    if (tid < 128) {
        const float4 a0 = s_red4[0][tid];
        const float4 a1 = s_red4[1][tid];
        const float4 a2 = s_red4[2][tid];
        const float4 a3 = s_red4[3][tid];
        const float4 bb = ((const float4*)b2)[tid];
        const float4 qq = ((const float4*)s_q)[tid];
        float4 o;
        o.x = a0.x + a1.x + a2.x + a3.x + bb.x + qq.x;
        o.y = a0.y + a1.y + a2.y + a3.y + bb.y + qq.y;
        o.z = a0.z + a1.z + a2.z + a3.z + bb.z + qq.z;
        o.w = a0.w + a1.w + a2.w + a3.w + bb.w + qq.w;
        ((float4*)(out + (size_t)b * DD))[tid] = o;
    }
}

extern "C" void kernel_launch(void* const* d_in, const int* in_sizes, int n_in,
                              void* d_out, int out_size, void* d_ws, size_t ws_size,
                              hipStream_t stream) {
    const float* q     = (const float*)d_in[0];
    const int*   heads = (const int*)  d_in[1];
    const int*   tails = (const int*)  d_in[2];
    const int*   rels  = (const int*)  d_in[3];
    const float* ent   = (const float*)d_in[4];
    const float* rel   = (const float*)d_in[5];
    const float* w1    = (const float*)d_in[6];
    const float* b1    = (const float*)d_in[7];
    const float* w2    = (const float*)d_in[8];
    const float* b2    = (const float*)d_in[9];
    float* out = (float*)d_out;

    const size_t need = (size_t)BB * NSPLIT * DD * sizeof(float);  // 16.78 MB
    if (ws_size >= need) {
        float* ws_pp = (float*)d_ws;
        dim3 g1(NSPLIT, BB, 1);
        gather_kernel<<<g1, 512, 0, stream>>>(q, heads, tails, rels, ent, rel, ws_pp);
        ffn_kernel<<<BB, 512, 0, stream>>>(q, ws_pp, w1, b1, w2, b2, out);
    } else {
        mono_kernel<<<BB, 512, 0, stream>>>(q, heads, tails, rels, ent, rel,
                                            w1, b1, w2, b2, out);
    }
}